// Round 1
// 1095.351 us; speedup vs baseline: 1.1429x; 1.1429x over previous
//
#include <hip/hip_runtime.h>
#include <cstdint>
#include <cstddef>

#define T_LEN    16384
#define BATCH    8
#define BT       (BATCH * T_LEN)   // 131072
#define NLAYERS  40

typedef unsigned short ushort_t;
typedef unsigned int   uint_t;
typedef __attribute__((ext_vector_type(8))) short    short8;   // 8 bf16 (4 VGPR) MFMA frag
typedef __attribute__((ext_vector_type(4))) float    float4v;  // MFMA accumulator
typedef __attribute__((ext_vector_type(8))) _Float16 half8;    // 16B of fp16

__device__ __forceinline__ ushort_t f2bf(float f) {
    union { float f; uint_t i; } v; v.f = f;
    uint_t r = (v.i + 0x7FFFu + ((v.i >> 16) & 1u)) >> 16;
    return (ushort_t)r;
}
__device__ __forceinline__ float fast_rcp(float x) {
#if __has_builtin(__builtin_amdgcn_rcpf)
    return __builtin_amdgcn_rcpf(x);
#else
    return 1.f / x;
#endif
}
__device__ __forceinline__ float tanh_fast(float x) {
    float e = __expf(2.f * x);
    return 1.f - 2.f * fast_rcp(e + 1.f);
}
__device__ __forceinline__ float sigmoid_fast(float x) {
    return fast_rcp(1.f + __expf(-x));
}
__device__ __forceinline__ float4v mfma16(short8 a, short8 b, float4v c) {
    return __builtin_amdgcn_mfma_f32_16x16x32_bf16(a, b, c, 0, 0, 0);
}

// ---------------------------------------------------------------------------
// Weight prep: convert fp32 weights -> bf16 MFMA B-fragment layout.
// Frag layout: B[k = (lane>>4)*8 + j][n = lane&15], stored [frag][lane][8] bf16.
// ---------------------------------------------------------------------------
__global__ __launch_bounds__(256) void k_prep(
    const float* __restrict__ filt_w, const float* __restrict__ gate_w,
    const float* __restrict__ res_w,  const float* __restrict__ skip_w,
    const float* __restrict__ end1_w, const float* __restrict__ end2_w,
    const float* __restrict__ filt_b, const float* __restrict__ gate_b,
    const float* __restrict__ res_b,  const float* __restrict__ skip_b,
    const float* __restrict__ end1_b, const float* __restrict__ end2_b,
    ushort_t* __restrict__ wfgF, ushort_t* __restrict__ wrF,
    ushort_t* __restrict__ bsF,  ushort_t* __restrict__ e1F, ushort_t* __restrict__ e2F,
    float* __restrict__ bfg, float* __restrict__ brb, float* __restrict__ bsum,
    float* __restrict__ b1,  float* __restrict__ b2)
{
    const int gt = blockIdx.x * blockDim.x + threadIdx.x;
    const int gs = gridDim.x * blockDim.x;

    // WfgFrag: [i][nt(4)][ks(2)] -> frag f = (i*4+nt)*2+ks. nt0,1 = filt o=0..31; nt2,3 = gate.
    for (int e = gt; e < NLAYERS * 4 * 2 * 512; e += gs) {
        int j = e & 7, lane = (e >> 3) & 63, f = e >> 9;
        int ks = f & 1, nt = (f >> 1) & 3, i = f >> 3;
        int ln = lane & 15, q = lane >> 4, c = q * 8 + j;
        int o = (nt & 1) * 16 + ln;
        float v = (nt < 2) ? filt_w[((i * 32 + o) * 32 + c) * 2 + ks]
                           : gate_w[((i * 32 + o) * 32 + c) * 2 + ks];
        wfgF[e] = f2bf(v);
    }
    // WrFrag: [i][nt(2)][ks(2)]
    for (int e = gt; e < NLAYERS * 2 * 2 * 512; e += gs) {
        int j = e & 7, lane = (e >> 3) & 63, f = e >> 9;
        int ks = f & 1, nt = (f >> 1) & 1, i = f >> 2;
        int ln = lane & 15, q = lane >> 4, c = q * 8 + j;
        int o = nt * 16 + ln;
        wrF[e] = f2bf(res_w[((i * 32 + o) * 32 + c) * 2 + ks]);
    }
    // BsFrag: [ks80(80)][nt(16)]; ks80 = i*2 + tap (tap0 = t-d, tap1 = t)
    for (int e = gt; e < 80 * 16 * 512; e += gs) {
        int j = e & 7, lane = (e >> 3) & 63, f = e >> 9;
        int nt = f & 15, ks80 = f >> 4;
        int i = ks80 >> 1, tap = ks80 & 1;
        int ln = lane & 15, q = lane >> 4, c = q * 8 + j;
        int o = nt * 16 + ln;
        bsF[e] = f2bf(skip_w[((i * 256 + o) * 32 + c) * 2 + tap]);
    }
    // End1/End2 frags: [ks(8)][nt(16)]
    for (int e = gt; e < 8 * 16 * 512; e += gs) {
        int j = e & 7, lane = (e >> 3) & 63, f = e >> 9;
        int nt = f & 15, ks = f >> 4;
        int ln = lane & 15, q = lane >> 4;
        int k = ks * 32 + q * 8 + j;
        int o = nt * 16 + ln;
        e1F[e] = f2bf(end1_w[o * 256 + k]);
        e2F[e] = f2bf(end2_w[o * 256 + k]);
    }
    // Biases
    for (int e = gt; e < NLAYERS * 64; e += gs) {
        int i = e >> 6, c = e & 63;
        bfg[e] = (c < 32) ? filt_b[i * 32 + c] : gate_b[i * 32 + (c - 32)];
    }
    for (int e = gt; e < NLAYERS * 32; e += gs) {
        int i = e >> 5, c = e & 31;
        brb[e] = res_b[i * 32 + c];
    }
    for (int e = gt; e < 256; e += gs) {
        float s = 0.f;
        for (int i = 0; i < NLAYERS; ++i) s += skip_b[i * 256 + e];
        bsum[e] = s;
        b1[e] = end1_b[e];
        b2[e] = end2_b[e];
    }
}

// ---------------------------------------------------------------------------
// Phase 1: input 1x1 conv  h0[bt][o] = sum_c w_in[o][c] * x[b][c][t] + b_in[o]
// ---------------------------------------------------------------------------
__global__ __launch_bounds__(256) void k_input(
    const float* __restrict__ x, const float* __restrict__ w_in,
    const float* __restrict__ b_in, _Float16* __restrict__ h16)
{
    __shared__ __align__(16) float ws[256 * 32];   // transposed [c][o], fp32
    for (int idx = threadIdx.x; idx < 256 * 32; idx += 256) {
        int o = idx >> 8, c = idx & 255;           // w_in flat = o*256 + c
        ws[c * 32 + o] = w_in[idx];
    }
    __syncthreads();
    const int bt = blockIdx.x * 256 + threadIdx.x;
    const float* xp = x + (size_t)(bt >> 14) * 256 * T_LEN + (bt & (T_LEN - 1));
    float acc[32];
#pragma unroll
    for (int o = 0; o < 32; ++o) acc[o] = b_in[o];
    for (int c = 0; c < 256; ++c) {
        float xv = xp[(size_t)c * T_LEN];
        const float4v* wr = (const float4v*)&ws[c * 32];
#pragma unroll
        for (int g = 0; g < 8; ++g) {
            float4v w4 = wr[g];
            acc[g * 4 + 0] += xv * w4[0];
            acc[g * 4 + 1] += xv * w4[1];
            acc[g * 4 + 2] += xv * w4[2];
            acc[g * 4 + 3] += xv * w4[3];
        }
    }
    half8* dst = (half8*)(h16 + (size_t)bt * 32);
#pragma unroll
    for (int g = 0; g < 4; ++g) {
        half8 v;
#pragma unroll
        for (int j = 0; j < 8; ++j) v[j] = (_Float16)acc[g * 8 + j];
        dst[g] = v;
    }
}

// ---------------------------------------------------------------------------
// Phase 2-start: fused filter+gate -> z for layer 0 only
// ---------------------------------------------------------------------------
__global__ __launch_bounds__(256) void k_fg(
    const _Float16* __restrict__ h16, const ushort_t* __restrict__ wfgF,
    const float* __restrict__ bfg, ushort_t* __restrict__ zAll,
    int layer, int dil)
{
    const int w = threadIdx.x >> 6, lane = threadIdx.x & 63;
    const int ln = lane & 15, q = lane >> 4;
    const int bt0 = (blockIdx.x * 4 + w) * 16;
    const int m = bt0 + ln;
    const int koff = q * 8;

    short8 a0 = {0, 0, 0, 0, 0, 0, 0, 0}, a1;
    {
        half8 hv = *(const half8*)(h16 + (size_t)m * 32 + koff);
#pragma unroll
        for (int j = 0; j < 8; ++j) a1[j] = (short)f2bf((float)hv[j]);
    }
    if ((m & (T_LEN - 1)) >= dil) {
        half8 hv = *(const half8*)(h16 + (size_t)(m - dil) * 32 + koff);
#pragma unroll
        for (int j = 0; j < 8; ++j) a0[j] = (short)f2bf((float)hv[j]);
    }

    const short8* wf8 = (const short8*)wfgF;
    const float4v vzero = {0.f, 0.f, 0.f, 0.f};
    float4v acc[4];
#pragma unroll
    for (int nt = 0; nt < 4; ++nt) {
        float4v c = vzero;
        short8 b0 = wf8[(((size_t)layer * 4 + nt) * 2 + 0) * 64 + lane];
        short8 b1 = wf8[(((size_t)layer * 4 + nt) * 2 + 1) * 64 + lane];
        c = mfma16(a0, b0, c);
        c = mfma16(a1, b1, c);
        acc[nt] = c;
    }

    const float bF0 = bfg[layer * 64 + ln],      bF1 = bfg[layer * 64 + 16 + ln];
    const float bG0 = bfg[layer * 64 + 32 + ln], bG1 = bfg[layer * 64 + 48 + ln];
    ushort_t* zl = zAll + (size_t)layer * BT * 32;
#pragma unroll
    for (int r = 0; r < 4; ++r) {
        int row = bt0 + q * 4 + r;
        float z0 = tanh_fast(acc[0][r] + bF0) * sigmoid_fast(acc[2][r] + bG0);
        float z1 = tanh_fast(acc[1][r] + bF1) * sigmoid_fast(acc[3][r] + bG1);
        zl[(size_t)row * 32 + ln]      = f2bf(z0);
        zl[(size_t)row * 32 + 16 + ln] = f2bf(z1);
    }
}

// ---------------------------------------------------------------------------
// Fused F(i) = res(i) + fg(i+1), restructured (R4):
//   - LDS holds only the res PARTIALS (c+bias), one mt-tile at a time: 18 KB
//     (was 66 KB with h added in C-layout via 16 scalar fp16 loads/lane/mt).
//   - h is added in phase B where lane owns row=ln: 2 vectorized half8 loads
//     per lane per mt replace 16 scalar 2B loads. Same fp32 add order for
//     tile0 ((c+br)+h); tile1 reassociated ((d+br)+h vs (h+d)+br), ~1 ulp.
//   - Occupancy 2 -> 4 blocks/CU (LDS 66->18 KB). Pad 36 keeps LDS writes
//     2-way (free) and phase-B b128 reads at the 8-cycle aggregate minimum.
// ---------------------------------------------------------------------------
__global__ __launch_bounds__(256) void k_resfg(
    const _Float16* __restrict__ hin, _Float16* __restrict__ hout,
    ushort_t* __restrict__ zAll,
    const ushort_t* __restrict__ wrF, const float* __restrict__ brb,
    const ushort_t* __restrict__ wfgF, const float* __restrict__ bfg,
    int layer, int dil, int dilN)
{
    __shared__ __align__(16) float lds[4][2][16 * 36];   // [wave][tile][row*36+col], 18 KB
    const int w = threadIdx.x >> 6, lane = threadIdx.x & 63;
    const int ln = lane & 15, q = lane >> 4;
    const int koff = q * 8;
    const int bt0 = (blockIdx.x * 4 + w) * 32;
    const ushort_t* zl = zAll + (size_t)layer * BT * 32;
    ushort_t* zo = zAll + (size_t)(layer + 1) * BT * 32;
    const short8* wr8 = (const short8*)wrF;
    const short8* wf8 = (const short8*)wfgF;
    const float4v vzero = {0.f, 0.f, 0.f, 0.f};
    const short8 zero8 = {0, 0, 0, 0, 0, 0, 0, 0};

    // res B frags (layer i)
    const short8 rb00 = wr8[(((size_t)layer * 2 + 0) * 2 + 0) * 64 + lane];
    const short8 rb01 = wr8[(((size_t)layer * 2 + 0) * 2 + 1) * 64 + lane];
    const short8 rb10 = wr8[(((size_t)layer * 2 + 1) * 2 + 0) * 64 + lane];
    const short8 rb11 = wr8[(((size_t)layer * 2 + 1) * 2 + 1) * 64 + lane];
    const float br0 = brb[layer * 32 + ln], br1 = brb[layer * 32 + 16 + ln];

    // fg B frags (layer i+1) — uniform across mt, hoisted
    const int L1 = layer + 1;
    short8 fb0[4], fb1[4];
#pragma unroll
    for (int nt = 0; nt < 4; ++nt) {
        fb0[nt] = wf8[(((size_t)L1 * 4 + nt) * 2 + 0) * 64 + lane];
        fb1[nt] = wf8[(((size_t)L1 * 4 + nt) * 2 + 1) * 64 + lane];
    }
    const float bF0 = bfg[L1 * 64 + ln],      bF1 = bfg[L1 * 64 + 16 + ln];
    const float bG0 = bfg[L1 * 64 + 32 + ln], bG1 = bfg[L1 * 64 + 48 + ln];

    float* t0 = &lds[w][0][0];
    float* t1 = &lds[w][1][0];

#pragma unroll
    for (int mt = 0; mt < 2; ++mt) {
        const int mb = bt0 + mt * 16;
        const int m = mb + ln;                 // this lane's row (A-side AND phase-B row)
        const int tln = m & (T_LEN - 1);
        // z loads (layer i) + early-issued h loads (consumed after barrier)
        short8 a1 = *(const short8*)(zl + (size_t)m * 32 + koff);
        short8 a0 = (tln >= dil) ? *(const short8*)(zl + (size_t)(m - dil) * 32 + koff) : zero8;
        short8 p1 = (tln >= dilN)       ? *(const short8*)(zl + (size_t)(m - dilN) * 32 + koff)       : zero8;
        short8 p0 = (tln >= dilN + dil) ? *(const short8*)(zl + (size_t)(m - dilN - dil) * 32 + koff) : zero8;
        const bool vld = (tln >= dilN);
        half8 hv1 = *(const half8*)(hin + (size_t)m * 32 + koff);
        half8 hv0 = {0, 0, 0, 0, 0, 0, 0, 0};
        if (vld) hv0 = *(const half8*)(hin + (size_t)(m - dilN) * 32 + koff);

        float4v c0 = mfma16(a0, rb00, vzero); c0 = mfma16(a1, rb01, c0);
        float4v c1 = mfma16(a0, rb10, vzero); c1 = mfma16(a1, rb11, c1);
        float4v d0 = mfma16(p0, rb00, vzero); d0 = mfma16(p1, rb01, d0);
        float4v d1 = mfma16(p0, rb10, vzero); d1 = mfma16(p1, rb11, d1);

        if (mt) __syncthreads();               // LDS reuse across mt tiles
#pragma unroll
        for (int r = 0; r < 4; ++r) {
            int row = q * 4 + r;
            t0[row * 36 + ln]      = c0[r] + br0;
            t0[row * 36 + 16 + ln] = c1[r] + br1;
            t1[row * 36 + ln]      = d0[r] + br0;    // invalid rows: d==0 -> br, masked below
            t1[row * 36 + 16 + ln] = d1[r] + br1;
        }
        __syncthreads();

        // Phase B: lane owns row=ln, k-chunk koff. Vectorized h add + transpose out.
        short8 fa1, fa0;
        half8 hw;
#pragma unroll
        for (int j = 0; j < 8; ++j) {
            float v1 = t0[ln * 36 + koff + j] + (float)hv1[j];
            fa1[j] = (short)f2bf(v1);
            hw[j]  = (_Float16)v1;
            float v0 = vld ? (t1[ln * 36 + koff + j] + (float)hv0[j]) : 0.f;
            fa0[j] = (short)f2bf(v0);
        }
        *(half8*)(hout + (size_t)m * 32 + koff) = hw;

        float4v acc[4];
#pragma unroll
        for (int nt = 0; nt < 4; ++nt) {
            float4v c = mfma16(fa0, fb0[nt], vzero);
            acc[nt] = mfma16(fa1, fb1[nt], c);
        }
#pragma unroll
        for (int r = 0; r < 4; ++r) {
            int row = mb + q * 4 + r;
            float z0 = tanh_fast(acc[0][r] + bF0) * sigmoid_fast(acc[2][r] + bG0);
            float z1 = tanh_fast(acc[1][r] + bF1) * sigmoid_fast(acc[3][r] + bG1);
            zo[(size_t)row * 32 + ln]      = f2bf(z0);
            zo[(size_t)row * 32 + 16 + ln] = f2bf(z1);
        }
    }
}

// ---------------------------------------------------------------------------
// Phase 3a: skip GEMM, restructured (R4): NO LDS, NO barriers.
// B panel (32 KB/layer, L2-resident weights) is read per-wave direct from
// global — L1 broadcasts the within-block duplication. Manual 2-deep register
// double-buffer: layer i+1's A and B frags are issued before layer i's MFMAs.
// Old structure drained vmcnt(0)+barrier twice per layer in 8-wave lockstep
// (measured 4600 cyc/block-layer vs ~860 L2-traffic bound, MfmaUtil 22.7%).
// XCD swizzle: consecutive row-blocks share dilated-tap reads -> same-XCD L2.
// ---------------------------------------------------------------------------
#define SG_LOAD(i, A0, A1, B0, B1) do {                                          \
    const int dil_ = 1 << ((i) % 10);                                            \
    const ushort_t* zl_ = zAll + (size_t)(i) * BT * 32;                          \
    _Pragma("unroll")                                                            \
    for (int mt_ = 0; mt_ < 4; ++mt_) {                                          \
        int m_ = mBase + mt_ * 16 + ln;                                          \
        int tln_ = m_ & (T_LEN - 1);                                             \
        A1[mt_] = *(const short8*)(zl_ + (size_t)m_ * 32 + koff);                \
        A0[mt_] = (tln_ >= dil_)                                                 \
                ? *(const short8*)(zl_ + (size_t)(m_ - dil_) * 32 + koff)        \
                : zero8;                                                         \
    }                                                                            \
    _Pragma("unroll")                                                            \
    for (int nt_ = 0; nt_ < 4; ++nt_) {                                          \
        B0[nt_] = bsrc[((size_t)((i) * 2 + 0) * 16 + wC * 4 + nt_) * 64 + lane]; \
        B1[nt_] = bsrc[((size_t)((i) * 2 + 1) * 16 + wC * 4 + nt_) * 64 + lane]; \
    }                                                                            \
} while (0)

#define SG_MMA(A0, A1, B0, B1) do {                                              \
    _Pragma("unroll")                                                            \
    for (int mt_ = 0; mt_ < 4; ++mt_)                                            \
        _Pragma("unroll")                                                        \
        for (int nt_ = 0; nt_ < 4; ++nt_) {                                      \
            acc[mt_][nt_] = mfma16(A0[mt_], B0[nt_], acc[mt_][nt_]);             \
            acc[mt_][nt_] = mfma16(A1[mt_], B1[nt_], acc[mt_][nt_]);             \
        }                                                                        \
} while (0)

__global__ __launch_bounds__(512, 2) void k_skip_gemm(
    const ushort_t* __restrict__ zAll, const ushort_t* __restrict__ bsF,
    const float* __restrict__ bsum, ushort_t* __restrict__ skipbuf)
{
    const int tid = threadIdx.x;
    const int w = tid >> 6, lane = tid & 63;
    const int wR = w >> 2, wC = w & 3;
    const int ln = lane & 15, q = lane >> 4, koff = q * 8;
    // XCD-aware bijective swizzle (gridDim.x = 1024, divisible by 8)
    const int bid = blockIdx.x;
    const int bsw = (bid & 7) * ((int)gridDim.x >> 3) + (bid >> 3);
    const int mBase = bsw * 128 + wR * 64;

    const float4v vzero = {0.f, 0.f, 0.f, 0.f};
    const short8 zero8 = {0, 0, 0, 0, 0, 0, 0, 0};
    const short8* bsrc = (const short8*)bsF;
    float4v acc[4][4];
#pragma unroll
    for (int mt = 0; mt < 4; ++mt)
#pragma unroll
        for (int nt = 0; nt < 4; ++nt) acc[mt][nt] = vzero;

    short8 xa0[4], xa1[4], xb0[4], xb1[4];
    short8 ya0[4], ya1[4], yb0[4], yb1[4];
    SG_LOAD(0, xa0, xa1, xb0, xb1);
#pragma unroll 2
    for (int i = 0; i < NLAYERS; i += 2) {
        SG_LOAD(i + 1, ya0, ya1, yb0, yb1);
        SG_MMA(xa0, xa1, xb0, xb1);
        if (i + 2 < NLAYERS) SG_LOAD(i + 2, xa0, xa1, xb0, xb1);
        SG_MMA(ya0, ya1, yb0, yb1);
    }

#pragma unroll
    for (int nt = 0; nt < 4; ++nt) {
        const int n = wC * 64 + nt * 16 + ln;
        const float bias = bsum[n];
#pragma unroll
        for (int mt = 0; mt < 4; ++mt)
#pragma unroll
            for (int r = 0; r < 4; ++r) {
                int row = mBase + mt * 16 + q * 4 + r;
                float v = fmaxf(acc[mt][nt][r] + bias, 0.f);
                skipbuf[(size_t)row * 256 + n] = f2bf(v);
            }
    }
}

// ---------------------------------------------------------------------------
// Phase 3b: fused end1+end2, restructured (R4): ldsS staging removed — B frags
// (e1F/e2F, 128 KB each, L2-resident) read direct from global. Only barrier
// left is the required one between the ldsA epilogue and GEMM2 (was 33).
// ---------------------------------------------------------------------------
__global__ __launch_bounds__(512) void k_end(
    const ushort_t* __restrict__ skipbuf, const ushort_t* __restrict__ e1F,
    const ushort_t* __restrict__ e2F, const float* __restrict__ b1,
    const float* __restrict__ b2, float* __restrict__ out)
{
    __shared__ __align__(16) ushort_t ldsA[64 * 512];   // 64 KB A2 frags
    const int tid = threadIdx.x;
    const int w = tid >> 6, lane = tid & 63;
    const int wR = w >> 2, wC = w & 3;
    const int ln = lane & 15, q = lane >> 4, koff = q * 8;
    const int mBase = blockIdx.x * 128 + wR * 64;

    const short8* e1s = (const short8*)e1F;
    const short8* e2s = (const short8*)e2F;
    const float4v vzero = {0.f, 0.f, 0.f, 0.f};
    float4v acc[4][4];
#pragma unroll
    for (int mt = 0; mt < 4; ++mt)
#pragma unroll
        for (int nt = 0; nt < 4; ++nt) acc[mt][nt] = vzero;

    // ---- GEMM1: out1 = relu(skip @ W1 + b1), no barriers ----
#pragma unroll 2
    for (int ks = 0; ks < 8; ++ks) {
        short8 a[4], bfr[4];
#pragma unroll
        for (int mt = 0; mt < 4; ++mt) {
            int m = mBase + mt * 16 + ln;
            a[mt] = *(const short8*)(skipbuf + (size_t)m * 256 + ks * 32 + koff);
        }
#pragma unroll
        for (int nt = 0; nt < 4; ++nt)
            bfr[nt] = e1s[((size_t)ks * 16 + wC * 4 + nt) * 64 + lane];
#pragma unroll
        for (int mt = 0; mt < 4; ++mt)
#pragma unroll
            for (int nt = 0; nt < 4; ++nt)
                acc[mt][nt] = mfma16(a[mt], bfr[nt], acc[mt][nt]);
    }
    // epilogue1: relu + bias -> ldsA in A-frag layout (bf16)
#pragma unroll
    for (int nt = 0; nt < 4; ++nt) {
        const int col = wC * 64 + nt * 16 + ln;
        const float bb = b1[col];
        const int fk = col >> 5;
        const int l2hi = ((col >> 3) & 3) << 4;
        const int j = col & 7;
#pragma unroll
        for (int mt = 0; mt < 4; ++mt) {
            const int fr = wR * 4 + mt;
#pragma unroll
            for (int r = 0; r < 4; ++r) {
                int lane2 = (q * 4 + r) | l2hi;
                float v = fmaxf(acc[mt][nt][r] + bb, 0.f);
                ldsA[((fr * 8 + fk) * 64 + lane2) * 8 + j] = f2bf(v);
            }
        }
    }
    __syncthreads();
    // ---- GEMM2: out = out1 @ W2 + b2, no further barriers ----
#pragma unroll
    for (int mt = 0; mt < 4; ++mt)
#pragma unroll
        for (int nt = 0; nt < 4; ++nt) acc[mt][nt] = vzero;
#pragma unroll 2
    for (int ks = 0; ks < 8; ++ks) {
        short8 a[4], bfr[4];
#pragma unroll
        for (int mt = 0; mt < 4; ++mt)
            a[mt] = ((const short8*)ldsA)[((size_t)(wR * 4 + mt) * 8 + ks) * 64 + lane];
#pragma unroll
        for (int nt = 0; nt < 4; ++nt)
            bfr[nt] = e2s[((size_t)ks * 16 + wC * 4 + nt) * 64 + lane];
#pragma unroll
        for (int mt = 0; mt < 4; ++mt)
#pragma unroll
            for (int nt = 0; nt < 4; ++nt)
                acc[mt][nt] = mfma16(a[mt], bfr[nt], acc[mt][nt]);
    }
#pragma unroll
    for (int nt = 0; nt < 4; ++nt) {
        const int n = wC * 64 + nt * 16 + ln;
        const float bb = b2[n];
#pragma unroll
        for (int mt = 0; mt < 4; ++mt)
#pragma unroll
            for (int r = 0; r < 4; ++r) {
                int row = mBase + mt * 16 + q * 4 + r;
                out[(size_t)row * 256 + n] = acc[mt][nt][r] + bb;
            }
    }
}

// ---------------------------------------------------------------------------
extern "C" void kernel_launch(void* const* d_in, const int* in_sizes, int n_in,
                              void* d_out, int out_size, void* d_ws, size_t ws_size,
                              hipStream_t stream)
{
    (void)in_sizes; (void)n_in; (void)out_size; (void)ws_size;
    const float* x      = (const float*)d_in[0];
    const float* w_in   = (const float*)d_in[1];
    const float* b_in   = (const float*)d_in[2];
    const float* filt_w = (const float*)d_in[3];
    const float* filt_b = (const float*)d_in[4];
    const float* gate_w = (const float*)d_in[5];
    const float* gate_b = (const float*)d_in[6];
    const float* res_w  = (const float*)d_in[7];
    const float* res_b  = (const float*)d_in[8];
    const float* skip_w = (const float*)d_in[9];
    const float* skip_b = (const float*)d_in[10];
    const float* end1_w = (const float*)d_in[11];
    const float* end1_b = (const float*)d_in[12];
    const float* end2_w = (const float*)d_in[13];
    const float* end2_b = (const float*)d_in[14];

    char* ws = (char*)d_ws;
    size_t off = 0;
    auto alloc = [&](size_t bytes) {
        char* p = ws + off;
        off += (bytes + 255) & ~(size_t)255;
        return p;
    };
    // Footprint discipline: R3 failed because total ws use (421.5 MB) exceeded
    // what R2 proved safe (413.1 MB) -> overflow corrupted harness pristine
    // copies. Fix kept: h ping-pong overlaid inside skipbuf (skipbuf written
    // only after all k_resfg launches are done; h is dead by then).
    // Total ~404.7 MB — unchanged this round.
    ushort_t* zAll    = (ushort_t*)alloc((size_t)NLAYERS * BT * 32 * 2);  // 335.5 MB
    ushort_t* skipbuf = (ushort_t*)alloc((size_t)BT * 256 * 2);           // 67 MB
    _Float16* hA      = (_Float16*)skipbuf;                               // overlay
    _Float16* hB      = (_Float16*)(skipbuf + (size_t)BT * 32);           // overlay
    ushort_t* wfgF    = (ushort_t*)alloc((size_t)NLAYERS * 4 * 2 * 512 * 2);
    ushort_t* wrF     = (ushort_t*)alloc((size_t)NLAYERS * 2 * 2 * 512 * 2);
    ushort_t* bsF     = (ushort_t*)alloc((size_t)80 * 16 * 512 * 2);
    ushort_t* e1F     = (ushort_t*)alloc((size_t)8 * 16 * 512 * 2);
    ushort_t* e2F     = (ushort_t*)alloc((size_t)8 * 16 * 512 * 2);
    float* bfg  = (float*)alloc((size_t)NLAYERS * 64 * 4);
    float* brb  = (float*)alloc((size_t)NLAYERS * 32 * 4);
    float* bsum = (float*)alloc(256 * 4);
    float* b1   = (float*)alloc(256 * 4);
    float* b2   = (float*)alloc(256 * 4);

    k_prep<<<256, 256, 0, stream>>>(filt_w, gate_w, res_w, skip_w, end1_w, end2_w,
                                    filt_b, gate_b, res_b, skip_b, end1_b, end2_b,
                                    wfgF, wrF, bsF, e1F, e2F, bfg, brb, bsum, b1, b2);
    k_input<<<BT / 256, 256, 0, stream>>>(x, w_in, b_in, hA);
    k_fg<<<BT / 64, 256, 0, stream>>>(hA, wfgF, bfg, zAll, 0, 1);
    for (int i = 0; i < NLAYERS - 1; ++i) {
        const _Float16* hin = (i & 1) ? hB : hA;
        _Float16*       ho  = (i & 1) ? hA : hB;
        int dil  = 1 << (i % 10);
        int dilN = 1 << ((i + 1) % 10);
        k_resfg<<<BT / 128, 256, 0, stream>>>(hin, ho, zAll, wrF, brb, wfgF, bfg,
                                              i, dil, dilN);
    }
    k_skip_gemm<<<BT / 128, 512, 0, stream>>>(zAll, bsF, bsum, skipbuf);
    k_end<<<BT / 128, 512, 0, stream>>>(skipbuf, e1F, e2F, b1, b2, (float*)d_out);
}